// Round 1
// baseline (949.705 us; speedup 1.0000x reference)
//
#include <hip/hip_runtime.h>
#include <hip/hip_bf16.h>
#include <math.h>

// ---------------- types / helpers ----------------
typedef __attribute__((ext_vector_type(8))) short s8v;    // 8 bf16 (4 VGPR) MFMA frag
typedef __attribute__((ext_vector_type(4))) float f32x4;  // MFMA accumulator

#define BM 32          // rows per workgroup (4 waves, N-split)
#define D_ 128
#define H_ 512

__device__ __forceinline__ unsigned short f2bf(float f) {
    union { float f; unsigned int u; } v; v.f = f;
    unsigned int r = (v.u + 0x7FFFu + ((v.u >> 16) & 1u)) >> 16;
    return (unsigned short)r;
}
__device__ __forceinline__ float bf2f(unsigned short h) {
    union { unsigned int u; float f; } v; v.u = ((unsigned int)h) << 16;
    return v.f;
}
__device__ __forceinline__ float softplus_f(float x) {
    return (x > 15.f) ? x : log1pf(__expf(x));
}
__device__ __forceinline__ float gelu_f(float z) {
    return 0.5f * z * (1.f + erff(z * 0.70710678118654752f));
}

// XOR swizzle (T2/G4): row-major D=128/512 bf16 LDS tiles are 16-way bank
// conflicts on ds_read_b128; flip bits 4..6 of byte offset by (row&7)<<4.
#define XS_BYTE(row, col) ((((row) * 256) + ((col) * 2)) ^ ((((row) & 7) << 4)))
#define US_BYTE(row, col) ((((row) * 1024) + ((col) * 2)) ^ ((((row) & 7) << 4)))

// ---------------- kernel 1: transpose weights to [N][K] bf16 ----------------
__global__ void prep_weights(const float* __restrict__ Wr, const float* __restrict__ Wb1,
                             const float* __restrict__ Wb2, const float* __restrict__ W1,
                             const float* __restrict__ W2, unsigned short* __restrict__ wt) {
    int i = blockIdx.x * 256 + threadIdx.x;
    if (i < 16384) { int n = i >> 7, k = i & 127; wt[i] = f2bf(Wr[k * 128 + n]); return; }
    i -= 16384;
    if (i < 65536) { int n = i >> 7, k = i & 127; wt[16384 + i] = f2bf(Wb1[k * 512 + n]); return; }
    i -= 65536;
    if (i < 65536) { int n = i >> 9, k = i & 511; wt[81920 + i] = f2bf(Wb2[k * 128 + n]); return; }
    i -= 65536;
    if (i < 65536) { int n = i >> 7, k = i & 127; wt[147456 + i] = f2bf(W1[k * 512 + n]); return; }
    i -= 65536;
    if (i < 65536) { int n = i >> 9, k = i & 511; wt[212992 + i] = f2bf(W2[k * 128 + n]); return; }
}

// ---------------- kernel 2: bucket scatter (build fixed-stride CSR) ----------------
__global__ void scatter_kernel(const int* __restrict__ ei, int E, int* __restrict__ cursor,
                               int* __restrict__ slots, int stride) {
    int t = blockIdx.x * 256 + threadIdx.x;
    if (t >= E) return;
    int src = ei[t];
    int dst = ei[E + t];
    int pos = atomicAdd(&cursor[dst], 1);
    if (pos < stride) slots[(long)dst * stride + pos] = src;
}

// ---------------- kernel 3: per-row aggregation (one wave per dst row) ----------------
__global__ void aggregate_kernel(const float* __restrict__ x, const int* __restrict__ cursor,
                                 const int* __restrict__ slots, float* __restrict__ agg,
                                 int N, int stride) {
    int wid = (blockIdx.x * blockDim.x + threadIdx.x) >> 6;
    int lane = threadIdx.x & 63;
    if (wid >= N) return;
    int cnt = cursor[wid];
    if (cnt > stride) cnt = stride;
    const int* sl = slots + (long)wid * stride;
    float a0 = 0.f, a1 = 0.f;
    for (int e = 0; e < cnt; e++) {
        int s = sl[e];
        const float* xr = x + (long)s * 128;
        a0 += xr[lane];
        a1 += xr[lane + 64];
    }
    agg[(long)wid * 128 + lane] = a0;
    agg[(long)wid * 128 + lane + 64] = a1;
}

// ---------------- kernel 4: fused per-row chain with MFMA ----------------
// BM=32 rows per WG, 4 waves. Wave w owns cols [32w,32w+32) for D=128 stages
// and cols [128w,128w+128) for H=512 stages. MFMA 16x16x32 bf16.
// A layout: lane l holds A[l%16][(l/16)*8 + i]; B: B[(l/16)*8+i][l%16];
// C/D: col=lane&15, row=(lane>>4)*4+reg (verified layout).
__global__ __launch_bounds__(256) void row_kernel(
    const float* __restrict__ x, const float* __restrict__ degree,
    const float* __restrict__ agg, const unsigned short* __restrict__ wt,
    const float* __restrict__ br, const float* __restrict__ bb1,
    const float* __restrict__ bb2, const float* __restrict__ g_rb,
    const float* __restrict__ b_rb, const float* __restrict__ b1,
    const float* __restrict__ b2, const float* __restrict__ g_n,
    const float* __restrict__ b_n, float* __restrict__ out) {
    const unsigned short* wt_r  = wt;
    const unsigned short* wt_b1 = wt + 16384;
    const unsigned short* wt_b2 = wt + 81920;
    const unsigned short* wt_1  = wt + 147456;
    const unsigned short* wt_2  = wt + 212992;

    __shared__ unsigned short xs[BM * 128];  // 8 KB   x as bf16 (swizzled)
    __shared__ unsigned short us[BM * 512];  // 32 KB  u, later v (swizzled)
    __shared__ unsigned short hs[BM * 128];  // 8 KB   h as bf16 (swizzled)
    __shared__ float red[BM][8][2];          // 2 KB   reduction scratch
    __shared__ float xstat[BM][2];
    __shared__ float gstat[BM][2];
    __shared__ float degs[BM];

    const int t = threadIdx.x;
    const int w = t >> 6;
    const int lane = t & 63;
    const int g = lane >> 4;
    const int c16 = lane & 15;
    const long rowbase = (long)blockIdx.x * BM;

    // ---- load x (f32), per-row stats in f32, store bf16 swizzled ----
    {
        int row = t >> 3, seg = t & 7;
        const float* xr = x + (rowbase + row) * 128 + seg * 16;
        float s = 0.f, s2 = 0.f;
        float vals[16];
        #pragma unroll
        for (int i = 0; i < 16; i += 4) {
            f32x4 v = *(const f32x4*)(xr + i);
            #pragma unroll
            for (int j = 0; j < 4; j++) { float f = v[j]; vals[i + j] = f; s += f; s2 += f * f; }
        }
        red[row][seg][0] = s; red[row][seg][1] = s2;
        #pragma unroll
        for (int i = 0; i < 8; i++) {
            unsigned int pk = (unsigned int)f2bf(vals[2 * i]) | ((unsigned int)f2bf(vals[2 * i + 1]) << 16);
            *(unsigned int*)((char*)xs + XS_BYTE(row, seg * 16 + 2 * i)) = pk;
        }
        if (t < BM) degs[t] = degree[rowbase + t];
    }
    __syncthreads();
    if (t < BM) {
        float s = 0.f, s2 = 0.f;
        #pragma unroll
        for (int i = 0; i < 8; i++) { s += red[t][i][0]; s2 += red[t][i][1]; }
        float mean = s * (1.f / 128.f);
        float var = s2 * (1.f / 128.f) - mean * mean;
        xstat[t][0] = mean; xstat[t][1] = rsqrtf(var + 1e-5f);
    }
    __syncthreads();

    // ---- stage 1+2: rate = sp(x@Wr+br); u = sp(x@Wb1+bb1) ----
    f32x4 acc1[2][2] = {};
    f32x4 acc2[2][8] = {};
    #pragma unroll
    for (int kt = 0; kt < 4; kt++) {
        int krow = kt * 32 + g * 8;
        s8v a0 = *(const s8v*)((const char*)xs + XS_BYTE(c16, krow));
        s8v a1 = *(const s8v*)((const char*)xs + XS_BYTE(16 + c16, krow));
        #pragma unroll
        for (int nt = 0; nt < 2; nt++) {
            int col = w * 32 + nt * 16 + c16;
            s8v b = *(const s8v*)&wt_r[col * 128 + krow];
            acc1[0][nt] = __builtin_amdgcn_mfma_f32_16x16x32_bf16(a0, b, acc1[0][nt], 0, 0, 0);
            acc1[1][nt] = __builtin_amdgcn_mfma_f32_16x16x32_bf16(a1, b, acc1[1][nt], 0, 0, 0);
        }
        #pragma unroll
        for (int nt = 0; nt < 8; nt++) {
            int col = w * 128 + nt * 16 + c16;
            s8v b = *(const s8v*)&wt_b1[col * 128 + krow];
            acc2[0][nt] = __builtin_amdgcn_mfma_f32_16x16x32_bf16(a0, b, acc2[0][nt], 0, 0, 0);
            acc2[1][nt] = __builtin_amdgcn_mfma_f32_16x16x32_bf16(a1, b, acc2[1][nt], 0, 0, 0);
        }
    }
    float rate[2][2][4];
    #pragma unroll
    for (int nt = 0; nt < 2; nt++) {
        float brv = br[w * 32 + nt * 16 + c16];
        #pragma unroll
        for (int mt = 0; mt < 2; mt++)
            #pragma unroll
            for (int r = 0; r < 4; r++)
                rate[mt][nt][r] = softplus_f(acc1[mt][nt][r] + brv);
    }
    #pragma unroll
    for (int nt = 0; nt < 8; nt++) {
        int col = w * 128 + nt * 16 + c16;
        float bbv = bb1[col];
        #pragma unroll
        for (int mt = 0; mt < 2; mt++)
            #pragma unroll
            for (int r = 0; r < 4; r++) {
                int row = mt * 16 + g * 4 + r;
                *(unsigned short*)((char*)us + US_BYTE(row, col)) = f2bf(softplus_f(acc2[mt][nt][r] + bbv));
            }
    }
    __syncthreads();

    // ---- stage 3: g0 = u@Wb2 + bb2, then LN -> gamma ----
    f32x4 acc3[2][2] = {};
    #pragma unroll
    for (int kt = 0; kt < 16; kt++) {
        int krow = kt * 32 + g * 8;
        s8v a0 = *(const s8v*)((const char*)us + US_BYTE(c16, krow));
        s8v a1 = *(const s8v*)((const char*)us + US_BYTE(16 + c16, krow));
        #pragma unroll
        for (int nt = 0; nt < 2; nt++) {
            int col = w * 32 + nt * 16 + c16;
            s8v b = *(const s8v*)&wt_b2[col * 512 + krow];
            acc3[0][nt] = __builtin_amdgcn_mfma_f32_16x16x32_bf16(a0, b, acc3[0][nt], 0, 0, 0);
            acc3[1][nt] = __builtin_amdgcn_mfma_f32_16x16x32_bf16(a1, b, acc3[1][nt], 0, 0, 0);
        }
    }
    float g0[2][2][4];
    #pragma unroll
    for (int nt = 0; nt < 2; nt++) {
        float bbv = bb2[w * 32 + nt * 16 + c16];
        #pragma unroll
        for (int mt = 0; mt < 2; mt++)
            #pragma unroll
            for (int r = 0; r < 4; r++)
                g0[mt][nt][r] = acc3[mt][nt][r] + bbv;
    }
    #pragma unroll
    for (int mt = 0; mt < 2; mt++) {
        #pragma unroll
        for (int r = 0; r < 4; r++) {
            float s = g0[mt][0][r] + g0[mt][1][r];
            float s2 = g0[mt][0][r] * g0[mt][0][r] + g0[mt][1][r] * g0[mt][1][r];
            #pragma unroll
            for (int m = 1; m < 16; m <<= 1) {
                s += __shfl_xor(s, m, 64);
                s2 += __shfl_xor(s2, m, 64);
            }
            if (c16 == 0) {
                int row = mt * 16 + g * 4 + r;
                red[row][w][0] = s; red[row][w][1] = s2;
            }
        }
    }
    __syncthreads();
    if (t < BM) {
        float s = red[t][0][0] + red[t][1][0] + red[t][2][0] + red[t][3][0];
        float s2 = red[t][0][1] + red[t][1][1] + red[t][2][1] + red[t][3][1];
        float mean = s * (1.f / 128.f);
        float var = s2 * (1.f / 128.f) - mean * mean;
        gstat[t][0] = mean; gstat[t][1] = rsqrtf(var + 1e-5f);
    }
    __syncthreads();

    // ---- stage 4: h = (rate*agg + gamma) / (1 + rate*deg + 1e-4), store bf16 ----
    #pragma unroll
    for (int nt = 0; nt < 2; nt++) {
        int col = w * 32 + nt * 16 + c16;
        float grb = g_rb[col], brb = b_rb[col];
        #pragma unroll
        for (int mt = 0; mt < 2; mt++)
            #pragma unroll
            for (int r = 0; r < 4; r++) {
                int row = mt * 16 + g * 4 + r;
                float gam = (g0[mt][nt][r] - gstat[row][0]) * gstat[row][1] * grb + brb;
                float ag = agg[(rowbase + row) * 128 + col];
                float rt = rate[mt][nt][r];
                float h = (rt * ag + gam) / (1.f + rt * degs[row] + 1e-4f);
                *(unsigned short*)((char*)hs + XS_BYTE(row, col)) = f2bf(h);
            }
    }
    __syncthreads();

    // ---- stage 5: v = gelu(h@W1 + b1) ----
    f32x4 acc5[2][8] = {};
    #pragma unroll
    for (int kt = 0; kt < 4; kt++) {
        int krow = kt * 32 + g * 8;
        s8v a0 = *(const s8v*)((const char*)hs + XS_BYTE(c16, krow));
        s8v a1 = *(const s8v*)((const char*)hs + XS_BYTE(16 + c16, krow));
        #pragma unroll
        for (int nt = 0; nt < 8; nt++) {
            int col = w * 128 + nt * 16 + c16;
            s8v b = *(const s8v*)&wt_1[col * 128 + krow];
            acc5[0][nt] = __builtin_amdgcn_mfma_f32_16x16x32_bf16(a0, b, acc5[0][nt], 0, 0, 0);
            acc5[1][nt] = __builtin_amdgcn_mfma_f32_16x16x32_bf16(a1, b, acc5[1][nt], 0, 0, 0);
        }
    }
    #pragma unroll
    for (int nt = 0; nt < 8; nt++) {
        int col = w * 128 + nt * 16 + c16;
        float b1v = b1[col];
        #pragma unroll
        for (int mt = 0; mt < 2; mt++)
            #pragma unroll
            for (int r = 0; r < 4; r++) {
                int row = mt * 16 + g * 4 + r;
                float z = acc5[mt][nt][r] + b1v;
                *(unsigned short*)((char*)us + US_BYTE(row, col)) = f2bf(gelu_f(z));
            }
    }
    __syncthreads();

    // ---- stage 6: out = v@W2 + b2 + x_res ----
    f32x4 acc6[2][2] = {};
    #pragma unroll
    for (int kt = 0; kt < 16; kt++) {
        int krow = kt * 32 + g * 8;
        s8v a0 = *(const s8v*)((const char*)us + US_BYTE(c16, krow));
        s8v a1 = *(const s8v*)((const char*)us + US_BYTE(16 + c16, krow));
        #pragma unroll
        for (int nt = 0; nt < 2; nt++) {
            int col = w * 32 + nt * 16 + c16;
            s8v b = *(const s8v*)&wt_2[col * 512 + krow];
            acc6[0][nt] = __builtin_amdgcn_mfma_f32_16x16x32_bf16(a0, b, acc6[0][nt], 0, 0, 0);
            acc6[1][nt] = __builtin_amdgcn_mfma_f32_16x16x32_bf16(a1, b, acc6[1][nt], 0, 0, 0);
        }
    }
    #pragma unroll
    for (int nt = 0; nt < 2; nt++) {
        int col = w * 32 + nt * 16 + c16;
        float b2v = b2[col], gnv = g_n[col], bnv = b_n[col];
        #pragma unroll
        for (int mt = 0; mt < 2; mt++)
            #pragma unroll
            for (int r = 0; r < 4; r++) {
                int row = mt * 16 + g * 4 + r;
                float xv = bf2f(*(const unsigned short*)((const char*)xs + XS_BYTE(row, col)));
                float xres = (xv - xstat[row][0]) * xstat[row][1] * gnv + bnv;
                out[(rowbase + row) * 128 + col] = acc6[mt][nt][r] + b2v + xres;
            }
    }
}

// ---------------- host ----------------
extern "C" void kernel_launch(void* const* d_in, const int* in_sizes, int n_in,
                              void* d_out, int out_size, void* d_ws, size_t ws_size,
                              hipStream_t stream) {
    const float* x   = (const float*)d_in[0];
    const int*   ei  = (const int*)d_in[1];
    const float* deg = (const float*)d_in[2];
    const float* Wr  = (const float*)d_in[3];
    const float* br  = (const float*)d_in[4];
    const float* Wb1 = (const float*)d_in[5];
    const float* bb1 = (const float*)d_in[6];
    const float* Wb2 = (const float*)d_in[7];
    const float* bb2 = (const float*)d_in[8];
    const float* grb = (const float*)d_in[9];
    const float* brb = (const float*)d_in[10];
    const float* W1  = (const float*)d_in[11];
    const float* b1  = (const float*)d_in[12];
    const float* W2  = (const float*)d_in[13];
    const float* b2  = (const float*)d_in[14];
    const float* gn  = (const float*)d_in[15];
    const float* bn  = (const float*)d_in[16];

    const int N = in_sizes[0] / 128;
    const int E = in_sizes[1] / 2;

    // workspace layout
    char* ws = (char*)d_ws;
    unsigned short* wt = (unsigned short*)ws;                    // 278528 bf16 = 557056 B
    size_t off = 557056;
    int* cursor = (int*)(ws + off); off += (size_t)N * 4;
    // pick slot stride that fits in ws (Poisson(16) degrees: 64 is ultra-safe)
    int stride = 64;
    size_t agg_bytes = (size_t)N * 128 * 4;
    if (off + (size_t)N * stride * 4 + agg_bytes > ws_size) stride = 32;
    int* slots = (int*)(ws + off); off += (size_t)N * stride * 4;
    float* aggp = (float*)(ws + off);

    hipMemsetAsync(cursor, 0, (size_t)N * 4, stream);
    prep_weights<<<278528 / 256, 256, 0, stream>>>(Wr, Wb1, Wb2, W1, W2, wt);
    scatter_kernel<<<(E + 255) / 256, 256, 0, stream>>>(ei, E, cursor, slots, stride);
    aggregate_kernel<<<(N + 3) / 4, 256, 0, stream>>>(x, cursor, slots, aggp, N, stride);
    row_kernel<<<N / BM, 256, 0, stream>>>(x, deg, aggp, wt, br, bb1, bb2, grb, brb,
                                           b1, b2, gn, bn, (float*)d_out);
}

// Round 2
// 466.550 us; speedup vs baseline: 2.0356x; 2.0356x over previous
//
#include <hip/hip_runtime.h>
#include <math.h>

// ---------------- types / helpers ----------------
typedef __attribute__((ext_vector_type(8))) short s8v;    // 8 bf16 MFMA frag
typedef __attribute__((ext_vector_type(4))) float f32x4;  // MFMA accumulator
typedef __attribute__((ext_vector_type(4))) unsigned int u32x4;
typedef __attribute__((ext_vector_type(2))) unsigned int u32x2;

#define BM 32   // rows per workgroup; 8 waves

__device__ __forceinline__ unsigned short f2bf(float f) {
    union { float f; unsigned int u; } v; v.f = f;
    return (unsigned short)((v.u + 0x7FFFu + ((v.u >> 16) & 1u)) >> 16);
}
__device__ __forceinline__ float bf2f(unsigned short h) {
    union { unsigned int u; float f; } v; v.u = ((unsigned int)h) << 16;
    return v.f;
}
// branch-free softplus: max(x,0) + log(1+exp(-|x|))
__device__ __forceinline__ float softplus_f(float x) {
    return fmaxf(x, 0.f) + __logf(1.f + __expf(-fabsf(x)));
}
// gelu via A&S 7.1.26 erf approx (|err| <= 1.5e-7)
__device__ __forceinline__ float gelu_f(float z) {
    float x = z * 0.70710678118654752f;
    float ax = fabsf(x);
    float t = __builtin_amdgcn_rcpf(1.f + 0.3275911f * ax);
    float p = t * (0.254829592f + t * (-0.284496736f + t * (1.421413741f +
              t * (-1.453152027f + t * 1.061405429f))));
    float er = 1.f - p * __expf(-x * x);
    er = (x < 0.f) ? -er : er;
    return 0.5f * z * (1.f + er);
}

// XOR swizzle (T2/G4): spread stride-256B/1024B row-major LDS rows across banks
#define XS_BYTE(row, col) ((((row) * 256) + ((col) * 2)) ^ ((((row) & 7) << 4)))
#define US_BYTE(row, col) ((((row) * 1024) + ((col) * 2)) ^ ((((row) & 7) << 4)))

// ---------------- kernel 1: weights -> fragment-ordered bf16 ----------------
// layout per weight (K x N): elem(k,n) at  (n>>4)*K*16 + ((k>>5)*4 + ((k>>3)&3))*128
//                                         + (n&15)*8 + (k&7)
// => a wave's 16B/lane frag load is 1024B contiguous (perfectly coalesced).
__global__ void prep_weights(const float* __restrict__ Wr, const float* __restrict__ Wb1,
                             const float* __restrict__ Wb2, const float* __restrict__ W1,
                             const float* __restrict__ W2, unsigned short* __restrict__ wt) {
    int i = blockIdx.x * 256 + threadIdx.x;
    if (i >= 278528) return;
    const float* src; int N, sh, base;
    if (i < 16384)       { src = Wr;  N = 128; sh = 11; base = 0; }
    else if (i < 81920)  { src = Wb1; N = 512; sh = 11; base = 16384; }
    else if (i < 147456) { src = Wb2; N = 128; sh = 13; base = 81920; }
    else if (i < 212992) { src = W1;  N = 512; sh = 11; base = 147456; }
    else                 { src = W2;  N = 128; sh = 13; base = 212992; }
    int j = i - base;
    int nT = j >> sh;
    int rem = j & ((1 << sh) - 1);
    int ktg = rem >> 7, rem2 = rem & 127;
    int c16 = rem2 >> 3, ii = rem2 & 7;
    int k = (ktg >> 2) * 32 + (ktg & 3) * 8 + ii;
    int n = nT * 16 + c16;
    wt[i] = f2bf(src[k * N + n]);
}

// ---------------- kernel 2: bucket scatter (fixed-stride CSR) ----------------
__global__ void scatter_kernel(const int* __restrict__ ei, int E, int* __restrict__ cursor,
                               int* __restrict__ slots, int stride) {
    int t = blockIdx.x * 256 + threadIdx.x;
    if (t >= E) return;
    int src = ei[t];
    int dst = ei[E + t];
    int pos = atomicAdd(&cursor[dst], 1);
    if (pos < stride) slots[(long)dst * stride + pos] = src;
}

// ---------------- kernel 3: per-row aggregation (one wave per dst row) ----------------
__global__ void aggregate_kernel(const float* __restrict__ x, const int* __restrict__ cursor,
                                 const int* __restrict__ slots, float* __restrict__ agg,
                                 int N, int stride) {
    int wid = (blockIdx.x * blockDim.x + threadIdx.x) >> 6;
    int lane = threadIdx.x & 63;
    if (wid >= N) return;
    int cnt = cursor[wid];
    if (cnt > stride) cnt = stride;
    const int* sl = slots + (long)wid * stride;
    float a0 = 0.f, a1 = 0.f;
    for (int e = 0; e < cnt; e++) {
        int s = sl[e];
        const float* xr = x + (long)s * 128;
        a0 += xr[lane];
        a1 += xr[lane + 64];
    }
    agg[(long)wid * 128 + lane] = a0;
    agg[(long)wid * 128 + lane + 64] = a1;
}

// ---------------- kernel 4: fused per-row chain, 8 waves ----------------
// D=128 stages (rate / gamma-GEMM / out): wave w owns cols [16w,16w+16), normal
//   orientation: mfma(x_frag, w_frag) -> lane holds rows g*4+r (+16*mt), col c16.
// H=512 stages (u / v): wave w owns cols [64w,64w+64), TRANSPOSED orientation:
//   mfma(w_frag, x_frag) -> lane holds row c16 (+16*mt), 4 consecutive H-cols
//   g*4..g*4+3 -> packed ds_write_b64.
__global__ __launch_bounds__(512, 4) void row_kernel(
    const float* __restrict__ x, const float* __restrict__ degree,
    const float* __restrict__ agg, const unsigned short* __restrict__ wt,
    const float* __restrict__ br, const float* __restrict__ bb1,
    const float* __restrict__ bb2, const float* __restrict__ g_rb,
    const float* __restrict__ b_rb, const float* __restrict__ b1,
    const float* __restrict__ b2, const float* __restrict__ g_n,
    const float* __restrict__ b_n, float* __restrict__ out) {
    const unsigned short* wt_r  = wt;
    const unsigned short* wt_b1 = wt + 16384;
    const unsigned short* wt_b2 = wt + 81920;
    const unsigned short* wt_1  = wt + 147456;
    const unsigned short* wt_2  = wt + 212992;

    __shared__ unsigned short xs[BM * 128];  // 8 KB  x bf16 (swizzled)
    __shared__ unsigned short us[BM * 512];  // 32 KB u, then v (swizzled)
    __shared__ unsigned short hs[BM * 128];  // 8 KB  h bf16 (swizzled)
    __shared__ float red[BM][16][2];         // 4 KB  reduction scratch
    __shared__ float xstat[BM][2];
    __shared__ float gstat[BM][2];
    __shared__ float degs[BM];

    const int t = threadIdx.x;
    const int w = t >> 6;
    const int lane = t & 63;
    const int g = lane >> 4;
    const int c16 = lane & 15;
    const long rowbase = (long)blockIdx.x * BM;

    // ---- stage 0: load x, stats partials, store bf16 swizzled (1 b128/thread) ----
    {
        int row = t >> 4, seg = t & 15;
        const float* xr = x + (rowbase + row) * 128 + seg * 8;
        f32x4 v0 = *(const f32x4*)xr;
        f32x4 v1 = *(const f32x4*)(xr + 4);
        float s = v0[0] + v0[1] + v0[2] + v0[3] + v1[0] + v1[1] + v1[2] + v1[3];
        float s2 = v0[0]*v0[0] + v0[1]*v0[1] + v0[2]*v0[2] + v0[3]*v0[3]
                 + v1[0]*v1[0] + v1[1]*v1[1] + v1[2]*v1[2] + v1[3]*v1[3];
        red[row][seg][0] = s; red[row][seg][1] = s2;
        u32x4 pk;
        pk[0] = (unsigned)f2bf(v0[0]) | ((unsigned)f2bf(v0[1]) << 16);
        pk[1] = (unsigned)f2bf(v0[2]) | ((unsigned)f2bf(v0[3]) << 16);
        pk[2] = (unsigned)f2bf(v1[0]) | ((unsigned)f2bf(v1[1]) << 16);
        pk[3] = (unsigned)f2bf(v1[2]) | ((unsigned)f2bf(v1[3]) << 16);
        *(u32x4*)((char*)xs + XS_BYTE(row, seg * 8)) = pk;
        if (t < BM) degs[t] = degree[rowbase + t];
    }
    __syncthreads();
    if (t < BM) {
        float s = 0.f, s2 = 0.f;
        #pragma unroll
        for (int i = 0; i < 16; i++) { s += red[t][i][0]; s2 += red[t][i][1]; }
        float mean = s * (1.f / 128.f);
        float var = s2 * (1.f / 128.f) - mean * mean;
        xstat[t][0] = mean; xstat[t][1] = rsqrtf(var + 1e-5f);
    }
    __syncthreads();

    // ---- stage 1+2: rate = sp(x@Wr+br) [normal]; u = sp(x@Wb1+bb1) [transposed] ----
    f32x4 acc1[2] = {};
    f32x4 acc2[2][4] = {};
    {
        const unsigned short* wr_w  = wt_r  + w * 2048;            // nTile=w, K=128
        const unsigned short* wb1_w = wt_b1 + (w * 4) * 2048;      // nTiles 4w..4w+3
        #pragma unroll
        for (int kt = 0; kt < 4; kt++) {
            s8v a0 = *(const s8v*)((const char*)xs + XS_BYTE(c16, kt * 32 + g * 8));
            s8v a1 = *(const s8v*)((const char*)xs + XS_BYTE(16 + c16, kt * 32 + g * 8));
            s8v bfr = *(const s8v*)(wr_w + kt * 512 + lane * 8);
            acc1[0] = __builtin_amdgcn_mfma_f32_16x16x32_bf16(a0, bfr, acc1[0], 0, 0, 0);
            acc1[1] = __builtin_amdgcn_mfma_f32_16x16x32_bf16(a1, bfr, acc1[1], 0, 0, 0);
            #pragma unroll
            for (int nt = 0; nt < 4; nt++) {
                s8v aw = *(const s8v*)(wb1_w + nt * 2048 + kt * 512 + lane * 8);
                acc2[0][nt] = __builtin_amdgcn_mfma_f32_16x16x32_bf16(aw, a0, acc2[0][nt], 0, 0, 0);
                acc2[1][nt] = __builtin_amdgcn_mfma_f32_16x16x32_bf16(aw, a1, acc2[1][nt], 0, 0, 0);
            }
        }
    }
    float rate[2][4];
    {
        float brv = br[w * 16 + c16];
        #pragma unroll
        for (int mt = 0; mt < 2; mt++)
            #pragma unroll
            for (int r = 0; r < 4; r++)
                rate[mt][r] = softplus_f(acc1[mt][r] + brv);
    }
    #pragma unroll
    for (int nt = 0; nt < 4; nt++) {
        f32x4 bb = *(const f32x4*)(bb1 + w * 64 + nt * 16 + g * 4);
        #pragma unroll
        for (int mt = 0; mt < 2; mt++) {
            u32x2 pp;
            pp[0] = (unsigned)f2bf(softplus_f(acc2[mt][nt][0] + bb[0]))
                  | ((unsigned)f2bf(softplus_f(acc2[mt][nt][1] + bb[1])) << 16);
            pp[1] = (unsigned)f2bf(softplus_f(acc2[mt][nt][2] + bb[2]))
                  | ((unsigned)f2bf(softplus_f(acc2[mt][nt][3] + bb[3])) << 16);
            *(u32x2*)((char*)us + US_BYTE(mt * 16 + c16, w * 64 + nt * 16 + g * 4)) = pp;
        }
    }
    __syncthreads();

    // ---- stage 3: g0 = u@Wb2 + bb2 [normal], LN stats ----
    f32x4 acc3[2] = {};
    {
        const unsigned short* wb2_w = wt_b2 + w * 8192;            // nTile=w, K=512
        #pragma unroll
        for (int kt = 0; kt < 16; kt++) {
            s8v a0 = *(const s8v*)((const char*)us + US_BYTE(c16, kt * 32 + g * 8));
            s8v a1 = *(const s8v*)((const char*)us + US_BYTE(16 + c16, kt * 32 + g * 8));
            s8v b = *(const s8v*)(wb2_w + kt * 512 + lane * 8);
            acc3[0] = __builtin_amdgcn_mfma_f32_16x16x32_bf16(a0, b, acc3[0], 0, 0, 0);
            acc3[1] = __builtin_amdgcn_mfma_f32_16x16x32_bf16(a1, b, acc3[1], 0, 0, 0);
        }
    }
    float g0[2][4];
    {
        float bbv = bb2[w * 16 + c16];
        #pragma unroll
        for (int mt = 0; mt < 2; mt++)
            #pragma unroll
            for (int r = 0; r < 4; r++)
                g0[mt][r] = acc3[mt][r] + bbv;
    }
    #pragma unroll
    for (int mt = 0; mt < 2; mt++) {
        #pragma unroll
        for (int r = 0; r < 4; r++) {
            float s = g0[mt][r];
            float s2 = s * s;
            #pragma unroll
            for (int m = 1; m < 16; m <<= 1) {
                s += __shfl_xor(s, m, 64);
                s2 += __shfl_xor(s2, m, 64);
            }
            if (c16 == 0) {
                int row = mt * 16 + g * 4 + r;
                red[row][w][0] = s; red[row][w][1] = s2;
            }
        }
    }
    __syncthreads();
    if (t < BM) {
        float s = 0.f, s2 = 0.f;
        #pragma unroll
        for (int i = 0; i < 8; i++) { s += red[t][i][0]; s2 += red[t][i][1]; }
        float mean = s * (1.f / 128.f);
        float var = s2 * (1.f / 128.f) - mean * mean;
        gstat[t][0] = mean; gstat[t][1] = rsqrtf(var + 1e-5f);
    }
    __syncthreads();

    // ---- stage 4: h = (rate*agg + gamma) * rcp(1 + rate*deg + 1e-4) ----
    {
        int col = w * 16 + c16;
        float grb = g_rb[col], brb = b_rb[col];
        #pragma unroll
        for (int mt = 0; mt < 2; mt++)
            #pragma unroll
            for (int r = 0; r < 4; r++) {
                int row = mt * 16 + g * 4 + r;
                float gam = (g0[mt][r] - gstat[row][0]) * gstat[row][1] * grb + brb;
                float ag = agg[(rowbase + row) * 128 + col];
                float rt = rate[mt][r];
                float h = (rt * ag + gam) * __builtin_amdgcn_rcpf(1.f + rt * degs[row] + 1e-4f);
                *(unsigned short*)((char*)hs + XS_BYTE(row, col)) = f2bf(h);
            }
    }
    __syncthreads();

    // ---- stage 5: v = gelu(h@W1 + b1) [transposed] ----
    f32x4 acc5[2][4] = {};
    {
        const unsigned short* w1_w = wt_1 + (w * 4) * 2048;
        #pragma unroll
        for (int kt = 0; kt < 4; kt++) {
            s8v h0 = *(const s8v*)((const char*)hs + XS_BYTE(c16, kt * 32 + g * 8));
            s8v h1 = *(const s8v*)((const char*)hs + XS_BYTE(16 + c16, kt * 32 + g * 8));
            #pragma unroll
            for (int nt = 0; nt < 4; nt++) {
                s8v aw = *(const s8v*)(w1_w + nt * 2048 + kt * 512 + lane * 8);
                acc5[0][nt] = __builtin_amdgcn_mfma_f32_16x16x32_bf16(aw, h0, acc5[0][nt], 0, 0, 0);
                acc5[1][nt] = __builtin_amdgcn_mfma_f32_16x16x32_bf16(aw, h1, acc5[1][nt], 0, 0, 0);
            }
        }
    }
    #pragma unroll
    for (int nt = 0; nt < 4; nt++) {
        f32x4 bv = *(const f32x4*)(b1 + w * 64 + nt * 16 + g * 4);
        #pragma unroll
        for (int mt = 0; mt < 2; mt++) {
            u32x2 pp;
            pp[0] = (unsigned)f2bf(gelu_f(acc5[mt][nt][0] + bv[0]))
                  | ((unsigned)f2bf(gelu_f(acc5[mt][nt][1] + bv[1])) << 16);
            pp[1] = (unsigned)f2bf(gelu_f(acc5[mt][nt][2] + bv[2]))
                  | ((unsigned)f2bf(gelu_f(acc5[mt][nt][3] + bv[3])) << 16);
            *(u32x2*)((char*)us + US_BYTE(mt * 16 + c16, w * 64 + nt * 16 + g * 4)) = pp;
        }
    }
    __syncthreads();

    // ---- stage 6: out = v@W2 + b2 + x_res [normal] ----
    f32x4 acc6[2] = {};
    {
        const unsigned short* w2_w = wt_2 + w * 8192;
        #pragma unroll
        for (int kt = 0; kt < 16; kt++) {
            s8v a0 = *(const s8v*)((const char*)us + US_BYTE(c16, kt * 32 + g * 8));
            s8v a1 = *(const s8v*)((const char*)us + US_BYTE(16 + c16, kt * 32 + g * 8));
            s8v b = *(const s8v*)(w2_w + kt * 512 + lane * 8);
            acc6[0] = __builtin_amdgcn_mfma_f32_16x16x32_bf16(a0, b, acc6[0], 0, 0, 0);
            acc6[1] = __builtin_amdgcn_mfma_f32_16x16x32_bf16(a1, b, acc6[1], 0, 0, 0);
        }
    }
    {
        int col = w * 16 + c16;
        float b2v = b2[col], gnv = g_n[col], bnv = b_n[col];
        #pragma unroll
        for (int mt = 0; mt < 2; mt++)
            #pragma unroll
            for (int r = 0; r < 4; r++) {
                int row = mt * 16 + g * 4 + r;
                float xv = bf2f(*(const unsigned short*)((const char*)xs + XS_BYTE(row, col)));
                float xres = (xv - xstat[row][0]) * xstat[row][1] * gnv + bnv;
                out[(rowbase + row) * 128 + col] = acc6[mt][r] + b2v + xres;
            }
    }
}

// ---------------- host ----------------
extern "C" void kernel_launch(void* const* d_in, const int* in_sizes, int n_in,
                              void* d_out, int out_size, void* d_ws, size_t ws_size,
                              hipStream_t stream) {
    const float* x   = (const float*)d_in[0];
    const int*   ei  = (const int*)d_in[1];
    const float* deg = (const float*)d_in[2];
    const float* Wr  = (const float*)d_in[3];
    const float* br  = (const float*)d_in[4];
    const float* Wb1 = (const float*)d_in[5];
    const float* bb1 = (const float*)d_in[6];
    const float* Wb2 = (const float*)d_in[7];
    const float* bb2 = (const float*)d_in[8];
    const float* grb = (const float*)d_in[9];
    const float* brb = (const float*)d_in[10];
    const float* W1  = (const float*)d_in[11];
    const float* b1  = (const float*)d_in[12];
    const float* W2  = (const float*)d_in[13];
    const float* b2  = (const float*)d_in[14];
    const float* gn  = (const float*)d_in[15];
    const float* bn  = (const float*)d_in[16];

    const int N = in_sizes[0] / 128;
    const int E = in_sizes[1] / 2;

    char* ws = (char*)d_ws;
    unsigned short* wt = (unsigned short*)ws;                    // 278528 bf16
    size_t off = 557056;
    int* cursor = (int*)(ws + off); off += (size_t)N * 4;
    int stride = 64;
    size_t agg_bytes = (size_t)N * 128 * 4;
    if (off + (size_t)N * stride * 4 + agg_bytes > ws_size) stride = 32;
    int* slots = (int*)(ws + off); off += (size_t)N * stride * 4;
    float* aggp = (float*)(ws + off);

    hipMemsetAsync(cursor, 0, (size_t)N * 4, stream);
    prep_weights<<<1088, 256, 0, stream>>>(Wr, Wb1, Wb2, W1, W2, wt);
    scatter_kernel<<<(E + 255) / 256, 256, 0, stream>>>(ei, E, cursor, slots, stride);
    aggregate_kernel<<<(N + 3) / 4, 256, 0, stream>>>(x, cursor, slots, aggp, N, stride);
    row_kernel<<<N / BM, 512, 0, stream>>>(x, deg, aggp, wt, br, bb1, bb2, grb, brb,
                                           b1, b2, gn, bn, (float*)d_out);
}

// Round 3
// 447.230 us; speedup vs baseline: 2.1235x; 1.0432x over previous
//
#include <hip/hip_runtime.h>
#include <hip/hip_bf16.h>
#include <math.h>

// ---------------- types / helpers ----------------
typedef __attribute__((ext_vector_type(8))) short s8v;    // 8 bf16 MFMA frag
typedef __attribute__((ext_vector_type(4))) float f32x4;  // MFMA accumulator
typedef __attribute__((ext_vector_type(4))) unsigned int u32x4;
typedef __attribute__((ext_vector_type(2))) unsigned int u32x2;

#define BM 32   // rows per workgroup; 8 waves

__device__ __forceinline__ unsigned short f2bf(float f) {
    union { float f; unsigned int u; } v; v.f = f;
    return (unsigned short)((v.u + 0x7FFFu + ((v.u >> 16) & 1u)) >> 16);
}
__device__ __forceinline__ float bf2f(unsigned short h) {
    union { unsigned int u; float f; } v; v.u = ((unsigned int)h) << 16;
    return v.f;
}
// packed f32x2 -> bf16x2 (v_cvt_pk_bf16_f32 via intrinsic; a in low half)
__device__ __forceinline__ unsigned int pk2(float a, float b) {
    union { __hip_bfloat162 h; unsigned int u; } v;
    v.h = __float22bfloat162_rn(make_float2(a, b));
    return v.u;
}
__device__ __forceinline__ float lo16(unsigned int u) {
    union { unsigned int u; float f; } v; v.u = u << 16; return v.f;
}
__device__ __forceinline__ float hi16(unsigned int u) {
    union { unsigned int u; float f; } v; v.u = u & 0xFFFF0000u; return v.f;
}
// branch-free softplus: max(x,0) + log(1+exp(-|x|))
__device__ __forceinline__ float softplus_f(float x) {
    return fmaxf(x, 0.f) + __logf(1.f + __expf(-fabsf(x)));
}
// gelu via A&S 7.1.26 erf approx (|err| <= 1.5e-7)
__device__ __forceinline__ float gelu_f(float z) {
    float x = z * 0.70710678118654752f;
    float ax = fabsf(x);
    float t = __builtin_amdgcn_rcpf(1.f + 0.3275911f * ax);
    float p = t * (0.254829592f + t * (-0.284496736f + t * (1.421413741f +
              t * (-1.453152027f + t * 1.061405429f))));
    float er = 1.f - p * __expf(-x * x);
    er = (x < 0.f) ? -er : er;
    return 0.5f * z * (1.f + er);
}

// XOR swizzle (T2/G4)
#define XS_BYTE(row, col) ((((row) * 256) + ((col) * 2)) ^ ((((row) & 7) << 4)))
#define US_BYTE(row, col) ((((row) * 1024) + ((col) * 2)) ^ ((((row) & 7) << 4)))

// ---------------- kernel 1: weights -> fragment-ordered bf16 ----------------
__global__ void prep_weights(const float* __restrict__ Wr, const float* __restrict__ Wb1,
                             const float* __restrict__ Wb2, const float* __restrict__ W1,
                             const float* __restrict__ W2, unsigned short* __restrict__ wt) {
    int i = blockIdx.x * 256 + threadIdx.x;
    if (i >= 278528) return;
    const float* src; int N, sh, base;
    if (i < 16384)       { src = Wr;  N = 128; sh = 11; base = 0; }
    else if (i < 81920)  { src = Wb1; N = 512; sh = 11; base = 16384; }
    else if (i < 147456) { src = Wb2; N = 128; sh = 13; base = 81920; }
    else if (i < 212992) { src = W1;  N = 512; sh = 11; base = 147456; }
    else                 { src = W2;  N = 128; sh = 13; base = 212992; }
    int j = i - base;
    int nT = j >> sh;
    int rem = j & ((1 << sh) - 1);
    int ktg = rem >> 7, rem2 = rem & 127;
    int c16 = rem2 >> 3, ii = rem2 & 7;
    int k = (ktg >> 2) * 32 + (ktg & 3) * 8 + ii;
    int n = nT * 16 + c16;
    wt[i] = f2bf(src[k * N + n]);
}

// ---------------- kernel 1b: x (f32) -> xbf (bf16) ----------------
__global__ void xcast_kernel(const float* __restrict__ x, unsigned short* __restrict__ xbf,
                             int n8) {
    int i = blockIdx.x * 256 + threadIdx.x;
    if (i >= n8) return;
    f32x4 v0 = *(const f32x4*)(x + (long)i * 8);
    f32x4 v1 = *(const f32x4*)(x + (long)i * 8 + 4);
    u32x4 pk;
    pk[0] = pk2(v0[0], v0[1]); pk[1] = pk2(v0[2], v0[3]);
    pk[2] = pk2(v1[0], v1[1]); pk[3] = pk2(v1[2], v1[3]);
    *(u32x4*)(xbf + (long)i * 8) = pk;
}

// ---------------- kernel 2: bucket scatter (fixed-stride CSR) ----------------
__global__ void scatter_kernel(const int* __restrict__ ei, int E, int* __restrict__ cursor,
                               int* __restrict__ slots, int stride) {
    int t = blockIdx.x * 256 + threadIdx.x;
    if (t >= E) return;
    int src = ei[t];
    int dst = ei[E + t];
    int pos = atomicAdd(&cursor[dst], 1);
    if (pos < stride) slots[(long)dst * stride + pos] = src;
}

// ---------------- kernel 3: per-row aggregation, bf16 gather ----------------
__global__ __launch_bounds__(256) void aggregate_kernel(
    const unsigned short* __restrict__ xbf, const int* __restrict__ cursor,
    const int* __restrict__ slots, unsigned short* __restrict__ aggbf,
    int N, int stride) {
    int wid = blockIdx.x * 4 + (threadIdx.x >> 6);
    int lane = threadIdx.x & 63;
    if (wid >= N) return;
    int cnt = cursor[wid];
    if (cnt > stride) cnt = stride;
    const int* sl = slots + (long)wid * stride;
    float a0 = 0.f, a1 = 0.f;
    int e = 0;
    for (; e + 4 <= cnt; e += 4) {
        unsigned int u0 = *(const unsigned int*)(xbf + (long)sl[e]     * 128 + lane * 2);
        unsigned int u1 = *(const unsigned int*)(xbf + (long)sl[e + 1] * 128 + lane * 2);
        unsigned int u2 = *(const unsigned int*)(xbf + (long)sl[e + 2] * 128 + lane * 2);
        unsigned int u3 = *(const unsigned int*)(xbf + (long)sl[e + 3] * 128 + lane * 2);
        a0 += lo16(u0) + lo16(u1) + lo16(u2) + lo16(u3);
        a1 += hi16(u0) + hi16(u1) + hi16(u2) + hi16(u3);
    }
    for (; e < cnt; e++) {
        unsigned int u = *(const unsigned int*)(xbf + (long)sl[e] * 128 + lane * 2);
        a0 += lo16(u); a1 += hi16(u);
    }
    *(unsigned int*)(aggbf + (long)wid * 128 + lane * 2) = pk2(a0, a1);
}

// ---------------- kernel 4: fused per-row chain, 8 waves ----------------
__global__ __launch_bounds__(512, 6) void row_kernel(
    const unsigned short* __restrict__ xbf, const float* __restrict__ degree,
    const unsigned short* __restrict__ aggbf, const unsigned short* __restrict__ wt,
    const float* __restrict__ br, const float* __restrict__ bb1,
    const float* __restrict__ bb2, const float* __restrict__ g_rb,
    const float* __restrict__ b_rb, const float* __restrict__ b1,
    const float* __restrict__ b2, const float* __restrict__ g_n,
    const float* __restrict__ b_n, float* __restrict__ out) {
    const unsigned short* wt_r  = wt;
    const unsigned short* wt_b1 = wt + 16384;
    const unsigned short* wt_b2 = wt + 81920;
    const unsigned short* wt_1  = wt + 147456;
    const unsigned short* wt_2  = wt + 212992;

    __shared__ unsigned short xs[BM * 128];  // 8 KB
    __shared__ unsigned short us[BM * 512];  // 32 KB
    __shared__ unsigned short hs[BM * 128];  // 8 KB
    __shared__ float red2[BM][17];           // 2176 B (padded: bank-conflict-free)
    __shared__ float xstat[BM][2];
    __shared__ float gstat[BM][2];
    __shared__ float degs[BM];

    const int t = threadIdx.x;
    const int w = t >> 6;
    const int lane = t & 63;
    const int g = lane >> 4;
    const int c16 = lane & 15;
    const long rowbase = (long)blockIdx.x * BM;

    // ---- stage 0: copy x-tile (bf16), row stats via 16-lane shfl reduce ----
    {
        int row = t >> 4, seg = t & 15;
        u32x4 v = *(const u32x4*)(xbf + (rowbase + row) * 128 + seg * 8);
        float s = 0.f, s2 = 0.f;
        #pragma unroll
        for (int j = 0; j < 4; j++) {
            float f0 = lo16(v[j]), f1 = hi16(v[j]);
            s += f0 + f1; s2 += f0 * f0 + f1 * f1;
        }
        #pragma unroll
        for (int m = 1; m < 16; m <<= 1) {
            s += __shfl_xor(s, m);
            s2 += __shfl_xor(s2, m);
        }
        if (seg == 0) {
            float mean = s * (1.f / 128.f);
            float var = s2 * (1.f / 128.f) - mean * mean;
            xstat[row][0] = mean; xstat[row][1] = rsqrtf(var + 1e-5f);
        }
        *(u32x4*)((char*)xs + XS_BYTE(row, seg * 8)) = v;
        if (t < BM) degs[t] = degree[rowbase + t];
    }
    __syncthreads();

    // ---- stage 1+2: rate = sp(x@Wr+br) [normal]; u = sp(x@Wb1+bb1) [transposed] ----
    f32x4 acc1[2] = {};
    f32x4 acc2[2][4] = {};
    {
        const unsigned short* wr_w  = wt_r  + w * 2048;
        const unsigned short* wb1_w = wt_b1 + (w * 4) * 2048;
        #pragma unroll
        for (int kt = 0; kt < 4; kt++) {
            s8v a0 = *(const s8v*)((const char*)xs + XS_BYTE(c16, kt * 32 + g * 8));
            s8v a1 = *(const s8v*)((const char*)xs + XS_BYTE(16 + c16, kt * 32 + g * 8));
            s8v bfr = *(const s8v*)(wr_w + kt * 512 + lane * 8);
            acc1[0] = __builtin_amdgcn_mfma_f32_16x16x32_bf16(a0, bfr, acc1[0], 0, 0, 0);
            acc1[1] = __builtin_amdgcn_mfma_f32_16x16x32_bf16(a1, bfr, acc1[1], 0, 0, 0);
            #pragma unroll
            for (int nt = 0; nt < 4; nt++) {
                s8v aw = *(const s8v*)(wb1_w + nt * 2048 + kt * 512 + lane * 8);
                acc2[0][nt] = __builtin_amdgcn_mfma_f32_16x16x32_bf16(aw, a0, acc2[0][nt], 0, 0, 0);
                acc2[1][nt] = __builtin_amdgcn_mfma_f32_16x16x32_bf16(aw, a1, acc2[1][nt], 0, 0, 0);
            }
        }
    }
    float rate[2][4];
    {
        float brv = br[w * 16 + c16];
        #pragma unroll
        for (int mt = 0; mt < 2; mt++)
            #pragma unroll
            for (int r = 0; r < 4; r++)
                rate[mt][r] = softplus_f(acc1[mt][r] + brv);
    }
    #pragma unroll
    for (int nt = 0; nt < 4; nt++) {
        f32x4 bb = *(const f32x4*)(bb1 + w * 64 + nt * 16 + g * 4);
        #pragma unroll
        for (int mt = 0; mt < 2; mt++) {
            u32x2 pp;
            pp[0] = pk2(softplus_f(acc2[mt][nt][0] + bb[0]), softplus_f(acc2[mt][nt][1] + bb[1]));
            pp[1] = pk2(softplus_f(acc2[mt][nt][2] + bb[2]), softplus_f(acc2[mt][nt][3] + bb[3]));
            *(u32x2*)((char*)us + US_BYTE(mt * 16 + c16, w * 64 + nt * 16 + g * 4)) = pp;
        }
    }
    __syncthreads();

    // ---- stage 3: g0 = u@Wb2 + bb2 [normal], LN stats via LDS cells ----
    f32x4 acc3[2] = {};
    {
        const unsigned short* wb2_w = wt_b2 + w * 8192;
        #pragma unroll
        for (int kt = 0; kt < 16; kt++) {
            s8v a0 = *(const s8v*)((const char*)us + US_BYTE(c16, kt * 32 + g * 8));
            s8v a1 = *(const s8v*)((const char*)us + US_BYTE(16 + c16, kt * 32 + g * 8));
            s8v b = *(const s8v*)(wb2_w + kt * 512 + lane * 8);
            acc3[0] = __builtin_amdgcn_mfma_f32_16x16x32_bf16(a0, b, acc3[0], 0, 0, 0);
            acc3[1] = __builtin_amdgcn_mfma_f32_16x16x32_bf16(a1, b, acc3[1], 0, 0, 0);
        }
    }
    float g0[2][4];
    {
        float bbv = bb2[w * 16 + c16];
        #pragma unroll
        for (int mt = 0; mt < 2; mt++)
            #pragma unroll
            for (int r = 0; r < 4; r++) {
                g0[mt][r] = acc3[mt][r] + bbv;
                // per-wave column-partial: sum over this wave's 16 cols happens
                // when t<BM threads read the 16 cells [row][0..15]... here each
                // lane contributes its single col value into cell [row][w*2+?]
            }
    }
    // each row's 128 cols = 8 waves x 16 lanes(c16); per-wave partial via shfl
    // is replaced by: lane writes its value to red2[row][c16] summed over w?
    // cells must be unique per (row, contributor): contributor = c16 within a
    // wave, but 8 waves share the same c16 range for DIFFERENT col blocks --
    // so reduce within the wave first over c16 is wrong (different rows).
    // Instead: cell [row][c16] is written by exactly one lane per wave... 8
    // waves would collide. Use per-wave partial sums over c16 via xor-shfl of
    // the 16-lane groups (4 shuffles), then cell [row][w].
    {
        #pragma unroll
        for (int mt = 0; mt < 2; mt++)
            #pragma unroll
            for (int r = 0; r < 4; r++) {
                float s = g0[mt][r];
                float s2 = s * s;
                #pragma unroll
                for (int m = 1; m < 16; m <<= 1) {
                    s += __shfl_xor(s, m);
                    s2 += __shfl_xor(s2, m);
                }
                if (c16 == 0) {
                    int row = mt * 16 + g * 4 + r;
                    red2[row][w * 2] = s; red2[row][w * 2 + 1] = s2;
                }
            }
    }
    __syncthreads();
    if (t < BM) {
        float s = 0.f, s2 = 0.f;
        #pragma unroll
        for (int i = 0; i < 8; i++) { s += red2[t][i * 2]; s2 += red2[t][i * 2 + 1]; }
        float mean = s * (1.f / 128.f);
        float var = s2 * (1.f / 128.f) - mean * mean;
        gstat[t][0] = mean; gstat[t][1] = rsqrtf(var + 1e-5f);
    }
    __syncthreads();

    // ---- stage 4: h = (rate*agg + gamma) * rcp(1 + rate*deg + 1e-4) ----
    {
        int col = w * 16 + c16;
        float grb = g_rb[col], brb = b_rb[col];
        #pragma unroll
        for (int mt = 0; mt < 2; mt++)
            #pragma unroll
            for (int r = 0; r < 4; r++) {
                int row = mt * 16 + g * 4 + r;
                float gam = (g0[mt][r] - gstat[row][0]) * gstat[row][1] * grb + brb;
                float ag = bf2f(aggbf[(rowbase + row) * 128 + col]);
                float rt = rate[mt][r];
                float h = (rt * ag + gam) * __builtin_amdgcn_rcpf(1.f + rt * degs[row] + 1e-4f);
                *(unsigned short*)((char*)hs + XS_BYTE(row, col)) = f2bf(h);
            }
    }
    __syncthreads();

    // ---- stage 5: v = gelu(h@W1 + b1) [transposed] ----
    f32x4 acc5[2][4] = {};
    {
        const unsigned short* w1_w = wt_1 + (w * 4) * 2048;
        #pragma unroll
        for (int kt = 0; kt < 4; kt++) {
            s8v h0 = *(const s8v*)((const char*)hs + XS_BYTE(c16, kt * 32 + g * 8));
            s8v h1 = *(const s8v*)((const char*)hs + XS_BYTE(16 + c16, kt * 32 + g * 8));
            #pragma unroll
            for (int nt = 0; nt < 4; nt++) {
                s8v aw = *(const s8v*)(w1_w + nt * 2048 + kt * 512 + lane * 8);
                acc5[0][nt] = __builtin_amdgcn_mfma_f32_16x16x32_bf16(aw, h0, acc5[0][nt], 0, 0, 0);
                acc5[1][nt] = __builtin_amdgcn_mfma_f32_16x16x32_bf16(aw, h1, acc5[1][nt], 0, 0, 0);
            }
        }
    }
    #pragma unroll
    for (int nt = 0; nt < 4; nt++) {
        f32x4 bv = *(const f32x4*)(b1 + w * 64 + nt * 16 + g * 4);
        #pragma unroll
        for (int mt = 0; mt < 2; mt++) {
            u32x2 pp;
            pp[0] = pk2(gelu_f(acc5[mt][nt][0] + bv[0]), gelu_f(acc5[mt][nt][1] + bv[1]));
            pp[1] = pk2(gelu_f(acc5[mt][nt][2] + bv[2]), gelu_f(acc5[mt][nt][3] + bv[3]));
            *(u32x2*)((char*)us + US_BYTE(mt * 16 + c16, w * 64 + nt * 16 + g * 4)) = pp;
        }
    }
    __syncthreads();

    // ---- stage 6: out = v@W2 + b2 + x_res [normal] ----
    f32x4 acc6[2] = {};
    {
        const unsigned short* w2_w = wt_2 + w * 8192;
        #pragma unroll
        for (int kt = 0; kt < 16; kt++) {
            s8v a0 = *(const s8v*)((const char*)us + US_BYTE(c16, kt * 32 + g * 8));
            s8v a1 = *(const s8v*)((const char*)us + US_BYTE(16 + c16, kt * 32 + g * 8));
            s8v b = *(const s8v*)(w2_w + kt * 512 + lane * 8);
            acc6[0] = __builtin_amdgcn_mfma_f32_16x16x32_bf16(a0, b, acc6[0], 0, 0, 0);
            acc6[1] = __builtin_amdgcn_mfma_f32_16x16x32_bf16(a1, b, acc6[1], 0, 0, 0);
        }
    }
    {
        int col = w * 16 + c16;
        float b2v = b2[col], gnv = g_n[col], bnv = b_n[col];
        #pragma unroll
        for (int mt = 0; mt < 2; mt++)
            #pragma unroll
            for (int r = 0; r < 4; r++) {
                int row = mt * 16 + g * 4 + r;
                float xv = bf2f(*(const unsigned short*)((const char*)xs + XS_BYTE(row, col)));
                float xres = (xv - xstat[row][0]) * xstat[row][1] * gnv + bnv;
                out[(rowbase + row) * 128 + col] = acc6[mt][r] + b2v + xres;
            }
    }
}

// ---------------- host ----------------
extern "C" void kernel_launch(void* const* d_in, const int* in_sizes, int n_in,
                              void* d_out, int out_size, void* d_ws, size_t ws_size,
                              hipStream_t stream) {
    const float* x   = (const float*)d_in[0];
    const int*   ei  = (const int*)d_in[1];
    const float* deg = (const float*)d_in[2];
    const float* Wr  = (const float*)d_in[3];
    const float* br  = (const float*)d_in[4];
    const float* Wb1 = (const float*)d_in[5];
    const float* bb1 = (const float*)d_in[6];
    const float* Wb2 = (const float*)d_in[7];
    const float* bb2 = (const float*)d_in[8];
    const float* grb = (const float*)d_in[9];
    const float* brb = (const float*)d_in[10];
    const float* W1  = (const float*)d_in[11];
    const float* b1  = (const float*)d_in[12];
    const float* W2  = (const float*)d_in[13];
    const float* b2  = (const float*)d_in[14];
    const float* gn  = (const float*)d_in[15];
    const float* bn  = (const float*)d_in[16];

    const int N = in_sizes[0] / 128;
    const int E = in_sizes[1] / 2;

    char* ws = (char*)d_ws;
    unsigned short* wt = (unsigned short*)ws;                  // 557056 B
    size_t off = 557056;
    int* cursor = (int*)(ws + off); off += (size_t)N * 4;
    unsigned short* xbf = (unsigned short*)(ws + off); off += (size_t)N * 128 * 2;
    unsigned short* aggbf = (unsigned short*)(ws + off); off += (size_t)N * 128 * 2;
    int stride = 64;
    if (off + (size_t)N * stride * 4 > ws_size) stride = 32;
    int* slots = (int*)(ws + off);

    hipMemsetAsync(cursor, 0, (size_t)N * 4, stream);
    prep_weights<<<1088, 256, 0, stream>>>(Wr, Wb1, Wb2, W1, W2, wt);
    xcast_kernel<<<(N * 16 + 255) / 256, 256, 0, stream>>>(x, xbf, N * 16);
    scatter_kernel<<<(E + 255) / 256, 256, 0, stream>>>(ei, E, cursor, slots, stride);
    aggregate_kernel<<<(N + 3) / 4, 256, 0, stream>>>(xbf, cursor, slots, aggbf, N, stride);
    row_kernel<<<N / BM, 512, 0, stream>>>(xbf, deg, aggbf, wt, br, bb1, bb2, grb, brb,
                                           b1, b2, gn, bn, (float*)d_out);
}